// Round 11
// baseline (5600.268 us; speedup 1.0000x reference)
//
#include <hip/hip_runtime.h>
#include <hip/hip_bf16.h>

#define T_STEPS 2048
#define BATCH   1024
#define NUNITS  128
#define ROWS    8
#define LOG2E   1.4426950408889634f

typedef __attribute__((ext_vector_type(8))) __bf16 bf16x8;
typedef __attribute__((ext_vector_type(4))) float  f32x4;
typedef __attribute__((ext_vector_type(2))) int    i32x2;

__device__ __forceinline__ float sigm_pre(float xs) {
    return __builtin_amdgcn_rcpf(1.0f + __builtin_amdgcn_exp2f(-xs));
}
__device__ __forceinline__ float tanh_pre(float xs) {
    return fmaf(-2.0f, __builtin_amdgcn_rcpf(1.0f + __builtin_amdgcn_exp2f(xs)), 1.0f);
}
// lanes 0-31 = a[self], lanes 32-63 = b[lane-32]  (verified R7)
__device__ __forceinline__ float swap_lo(float a, float b) {
    i32x2 r = __builtin_amdgcn_permlane32_swap(__builtin_bit_cast(int, a),
                                               __builtin_bit_cast(int, b),
                                               false, false);
    return __builtin_bit_cast(float, r[0]);
}

// ---------------- embedding pre-pass (unchanged/verified)
__global__ __launch_bounds__(256) void emb_kernel(const float* __restrict__ x,
                                                  const float* __restrict__ Wemb,
                                                  const float* __restrict__ bemb,
                                                  ushort* __restrict__ e_out) {
    int g = blockIdx.x * 256 + threadIdx.x;   // g = t*1024 + b
    int t = g >> 10;
    int b = g & 1023;
    const float* xr = x + ((size_t)b * T_STEPS + t) * 64;

    float4 xv[16];
#pragma unroll
    for (int i = 0; i < 16; i++) xv[i] = ((const float4*)xr)[i];

    float acc[24];
#pragma unroll
    for (int j = 0; j < 24; j++) acc[j] = bemb[j];

#pragma unroll
    for (int d = 0; d < 64; d++) {
        float xs = ((const float*)xv)[d];
#pragma unroll
        for (int j = 0; j < 24; j++) acc[j] = fmaf(xs, Wemb[d * 24 + j], acc[j]);
    }

    uint outp[12];
#pragma unroll
    for (int p = 0; p < 12; p++) {
        float lo = __builtin_amdgcn_rcpf(1.0f + __builtin_amdgcn_exp2f(-LOG2E * acc[2 * p]));
        float hi = __builtin_amdgcn_rcpf(1.0f + __builtin_amdgcn_exp2f(-LOG2E * acc[2 * p + 1]));
        ushort ulo = __builtin_bit_cast(ushort, (__bf16)lo);
        ushort uhi = __builtin_bit_cast(ushort, (__bf16)hi);
        outp[p] = (uint)ulo | ((uint)uhi << 16);
    }
    uint4* dst = (uint4*)(e_out + (size_t)g * 24);
#pragma unroll
    for (int q = 0; q < 3; q++) dst[q] = ((const uint4*)outp)[q];
}

// ---------------- ABLATION of the verified R7 kernel (1360us, conflicts-trivial).
// VARIANT: 0=full  1=no-trans  2=no-ds_read  3=no-barrier  4=no-z-MFMA.
// All variants run the full 2048-step loop with identical prologue/e-traffic;
// V1..V4 produce garbage h (V0 dispatched LAST overwrites all of d_out).
template <int VARIANT>
__global__ __launch_bounds__(512, 1) void lstm_kernel(
    const ushort* __restrict__ e_ws,
    const float* __restrict__ Wf, const float* __restrict__ bf_,
    const float* __restrict__ Wi, const float* __restrict__ bi_,
    const float* __restrict__ Wg, const float* __restrict__ bg_,
    const float* __restrict__ Wo, const float* __restrict__ bo_,
    const float* __restrict__ Wout, const float* __restrict__ bout,
    float* __restrict__ out) {
    __shared__ __align__(16) __bf16 zfrag[2][4][4][16][8];   // 8 KiB

    const int tid  = threadIdx.x;
    const int lane = tid & 63;
    const int wv   = tid >> 6;
    const int l15  = lane & 15;
    const int kg   = lane >> 4;
    const int r0   = blockIdx.x * ROWS;

    const float* Wp[4] = {Wf, Wi, Wg, Wo};
    const float gsc[4] = {LOG2E, LOG2E, 2.0f * LOG2E, LOG2E};
    const int ucol = wv * 16 + l15;
    bf16x8 wreg[4][5];
#pragma unroll
    for (int gt = 0; gt < 4; gt++) {
#pragma unroll
        for (int ks = 0; ks < 5; ks++) {
#pragma unroll
            for (int j = 0; j < 8; j++) {
                int k = ks * 32 + kg * 8 + j;
                float v = 0.0f;
                if (k < 128) v = Wp[gt][(24 + k) * NUNITS + ucol];
                else if (k < 152) v = Wp[gt][(k - 128) * NUNITS + ucol];
                wreg[gt][ks][j] = (__bf16)(v * gsc[gt]);
            }
        }
    }
    const float* Bp[4] = {bf_, bi_, bg_, bo_};
    f32x4 bias[4];
#pragma unroll
    for (int gt = 0; gt < 4; gt++) {
        float bv = Bp[gt][ucol] * gsc[gt];
#pragma unroll
        for (int r = 0; r < 4; r++) bias[gt][r] = bv;
    }

    for (int i = tid; i < 2 * 4 * 4 * 16 * 8; i += 512) ((__bf16*)zfrag)[i] = (__bf16)0.0f;

    const __bf16* zrd = &zfrag[0][0][kg][l15][0];
    const int q2 = lane >> 4;
    const int row_c0 = ((q2 & 1) << 2) | ((q2 >> 1) << 1);   // [0,4,2,6][q2]
    __bf16* zwr = &zfrag[0][ucol >> 5][(ucol >> 3) & 3][row_c0][ucol & 7];

    const ushort* elbase = e_ws + ((size_t)(r0 + (l15 & 7)) * 24 + kg * 8);
    const bool eload = (kg < 3) && (l15 < 8);
    bf16x8 e0, e1;
#pragma unroll
    for (int j = 0; j < 8; j++) { e0[j] = (__bf16)0.0f; e1[j] = (__bf16)0.0f; }
    if (eload) {
        e0 = *(const bf16x8*)(const void*)(elbase);
        e1 = *(const bf16x8*)(const void*)(elbase + 24576);
    }

    __syncthreads();

    float c0 = 0.0f, c1 = 0.0f;
    f32x4 eA[4], eB[4];
#pragma unroll
    for (int gt = 0; gt < 4; gt++)
        eA[gt] = __builtin_amdgcn_mfma_f32_16x16x32_bf16(e0, wreg[gt][4], bias[gt], 0, 0, 0);
    if (eload) e0 = *(const bf16x8*)(const void*)(elbase + 2 * 24576);

    auto STEP = [&](int t, int P, f32x4 (&cur)[4], f32x4 (&nxt)[4], bf16x8& enext) {
        const __bf16* zb = zrd + P * 2048;
        bf16x8 z0, z1, z2, z3;
        if constexpr (VARIANT != 2) {
            z0 = *(const bf16x8*)(const void*)(zb);
            z1 = *(const bf16x8*)(const void*)(zb + 512);
            z2 = *(const bf16x8*)(const void*)(zb + 1024);
            z3 = *(const bf16x8*)(const void*)(zb + 1536);
        } else {   // V2: register stand-ins, no LDS read
            z0 = wreg[0][0]; z1 = wreg[1][1]; z2 = wreg[2][2]; z3 = wreg[3][3];
        }

        f32x4 acc[4];
        if constexpr (VARIANT != 4) {
#pragma unroll
            for (int gt = 0; gt < 4; gt++) {
                acc[gt] = __builtin_amdgcn_mfma_f32_16x16x32_bf16(z0, wreg[gt][0], cur[gt], 0, 0, 0);
                acc[gt] = __builtin_amdgcn_mfma_f32_16x16x32_bf16(z1, wreg[gt][1], acc[gt], 0, 0, 0);
                acc[gt] = __builtin_amdgcn_mfma_f32_16x16x32_bf16(z2, wreg[gt][2], acc[gt], 0, 0, 0);
                acc[gt] = __builtin_amdgcn_mfma_f32_16x16x32_bf16(z3, wreg[gt][3], acc[gt], 0, 0, 0);
            }
        } else {   // V4: keep z->acc->trans dependency with VALU instead of MFMA
#pragma unroll
            for (int gt = 0; gt < 4; gt++) {
                acc[gt] = cur[gt];
                acc[gt][0] += (float)z0[gt];
                acc[gt][1] += (float)z1[gt];
                acc[gt][2] += (float)z2[gt];
                acc[gt][3] += (float)z3[gt];
            }
        }

#pragma unroll
        for (int gt = 0; gt < 4; gt++)
            nxt[gt] = __builtin_amdgcn_mfma_f32_16x16x32_bf16(enext, wreg[gt][4], bias[gt], 0, 0, 0);
        {
            int tf = t + 3; if (tf > T_STEPS - 1) tf = T_STEPS - 1;
            if (eload) enext = *(const bf16x8*)(const void*)(elbase + (size_t)tf * 24576);
        }

        float g0[4], g1[4];
#pragma unroll
        for (int gt = 0; gt < 4; gt++) {
            g0[gt] = swap_lo(acc[gt][0], acc[gt][2]);
            g1[gt] = swap_lo(acc[gt][1], acc[gt][3]);
        }

        float h0, h1;
        if constexpr (VARIANT != 1) {
            float fg0 = sigm_pre(g0[0]), fg1 = sigm_pre(g1[0]);
            float ig0 = sigm_pre(g0[1]), ig1 = sigm_pre(g1[1]);
            float gg0 = tanh_pre(g0[2]), gg1 = tanh_pre(g1[2]);
            float og0 = sigm_pre(g0[3]), og1 = sigm_pre(g1[3]);
            c0 = fmaf(c0, fg0, ig0 * gg0);
            c1 = fmaf(c1, fg1, ig1 * gg1);
            h0 = tanh_pre(2.0f * LOG2E * c0) * og0;
            h1 = tanh_pre(2.0f * LOG2E * c1) * og1;
        } else {   // V1: same dep structure, full-rate VALU instead of trans pipe
            float fg0 = fmaf(g0[0], 0.25f, 0.5f), fg1 = fmaf(g1[0], 0.25f, 0.5f);
            float ig0 = fmaf(g0[1], 0.25f, 0.5f), ig1 = fmaf(g1[1], 0.25f, 0.5f);
            float gg0 = g0[2] * 0.25f,            gg1 = g1[2] * 0.25f;
            float og0 = fmaf(g0[3], 0.25f, 0.5f), og1 = fmaf(g1[3], 0.25f, 0.5f);
            c0 = fmaf(c0, fg0, ig0 * gg0);
            c1 = fmaf(c1, fg1, ig1 * gg1);
            h0 = (c0 * 0.5f) * og0;
            h1 = (c1 * 0.5f) * og1;
        }

        __bf16* zw = zwr + (P ^ 1) * 2048;
        zw[0] = (__bf16)h0;
        zw[8] = (__bf16)h1;

        if constexpr (VARIANT != 3) {
            asm volatile("s_waitcnt lgkmcnt(0)" ::: "memory");
            __builtin_amdgcn_s_barrier();
            __builtin_amdgcn_sched_barrier(0);
        } else {
            __builtin_amdgcn_sched_barrier(0);   // keep loop structure, no sync
        }
    };

    for (int t = 0; t < T_STEPS; t += 2) {
        STEP(t,     0, eA, eB, e1);
        STEP(t + 1, 1, eB, eA, e0);
    }

    if (tid < ROWS) {
        float s = bout[0];
#pragma unroll
        for (int k = 0; k < NUNITS; k++)
            s += (float)zfrag[0][k >> 5][(k >> 3) & 3][tid][k & 7] * Wout[k];
        out[r0 + tid] = __builtin_amdgcn_rcpf(1.0f + __builtin_amdgcn_exp2f(-LOG2E * s));
    }
}

extern "C" void kernel_launch(void* const* d_in, const int* in_sizes, int n_in,
                              void* d_out, int out_size, void* d_ws, size_t ws_size,
                              hipStream_t stream) {
    const float* x     = (const float*)d_in[0];
    const float* Wemb  = (const float*)d_in[1];
    const float* bemb  = (const float*)d_in[2];
    const float* Wf    = (const float*)d_in[3];
    const float* bf_   = (const float*)d_in[4];
    const float* Wi    = (const float*)d_in[5];
    const float* bi_   = (const float*)d_in[6];
    const float* Wg    = (const float*)d_in[7];
    const float* bg_   = (const float*)d_in[8];
    const float* Wo    = (const float*)d_in[9];
    const float* bo_   = (const float*)d_in[10];
    const float* Wout  = (const float*)d_in[11];
    const float* bout  = (const float*)d_in[12];
    float* out = (float*)d_out;
    ushort* e_ws = (ushort*)d_ws;   // [T][B][24] bf16, ~96 MB

    int nrows = BATCH * T_STEPS;
    emb_kernel<<<nrows / 256, 256, 0, stream>>>(x, Wemb, bemb, e_ws);

    // Ablation dispatches: V1..V4 (garbage h, d_out scribble), V0 LAST (correct,
    // overwrites every d_out element -> validated output is V0's).
    lstm_kernel<1><<<BATCH / ROWS, 512, 0, stream>>>(e_ws, Wf, bf_, Wi, bi_, Wg, bg_, Wo, bo_, Wout, bout, out);
    lstm_kernel<2><<<BATCH / ROWS, 512, 0, stream>>>(e_ws, Wf, bf_, Wi, bi_, Wg, bg_, Wo, bo_, Wout, bout, out);
    lstm_kernel<3><<<BATCH / ROWS, 512, 0, stream>>>(e_ws, Wf, bf_, Wi, bi_, Wg, bg_, Wo, bo_, Wout, bout, out);
    lstm_kernel<4><<<BATCH / ROWS, 512, 0, stream>>>(e_ws, Wf, bf_, Wi, bi_, Wg, bg_, Wo, bo_, Wout, bout, out);
    lstm_kernel<0><<<BATCH / ROWS, 512, 0, stream>>>(e_ws, Wf, bf_, Wi, bi_, Wg, bg_, Wo, bo_, Wout, bout, out);
}

// Round 12
// 1541.037 us; speedup vs baseline: 3.6341x; 3.6341x over previous
//
#include <hip/hip_runtime.h>
#include <hip/hip_bf16.h>

#define T_STEPS 2048
#define BATCH   1024
#define NUNITS  128
#define ROWS    8
#define LOG2E   1.4426950408889634f

typedef __attribute__((ext_vector_type(8))) __bf16 bf16x8;
typedef __attribute__((ext_vector_type(4))) float  f32x4;
typedef __attribute__((ext_vector_type(2))) int    i32x2;
typedef __attribute__((ext_vector_type(4))) int    int4v;

__device__ __forceinline__ float sigm_pre(float xs) {
    return __builtin_amdgcn_rcpf(1.0f + __builtin_amdgcn_exp2f(-xs));
}
__device__ __forceinline__ float tanh_pre(float xs) {
    return fmaf(-2.0f, __builtin_amdgcn_rcpf(1.0f + __builtin_amdgcn_exp2f(xs)), 1.0f);
}
// lanes 0-31 = a[self], lanes 32-63 = b[lane-32]  (verified R7)
__device__ __forceinline__ float swap_lo(float a, float b) {
    i32x2 r = __builtin_amdgcn_permlane32_swap(__builtin_bit_cast(int, a),
                                               __builtin_bit_cast(int, b),
                                               false, false);
    return __builtin_bit_cast(float, r[0]);
}

// ---------------- embedding pre-pass (HBM-bound, verified)
__global__ __launch_bounds__(256) void emb_kernel(const float* __restrict__ x,
                                                  const float* __restrict__ Wemb,
                                                  const float* __restrict__ bemb,
                                                  ushort* __restrict__ e_out) {
    int g = blockIdx.x * 256 + threadIdx.x;   // g = t*1024 + b
    int t = g >> 10;
    int b = g & 1023;
    const float* xr = x + ((size_t)b * T_STEPS + t) * 64;

    float4 xv[16];
#pragma unroll
    for (int i = 0; i < 16; i++) xv[i] = ((const float4*)xr)[i];

    float acc[24];
#pragma unroll
    for (int j = 0; j < 24; j++) acc[j] = bemb[j];

#pragma unroll
    for (int d = 0; d < 64; d++) {
        float xs = ((const float*)xv)[d];
#pragma unroll
        for (int j = 0; j < 24; j++) acc[j] = fmaf(xs, Wemb[d * 24 + j], acc[j]);
    }

    uint outp[12];
#pragma unroll
    for (int p = 0; p < 12; p++) {
        float lo = __builtin_amdgcn_rcpf(1.0f + __builtin_amdgcn_exp2f(-LOG2E * acc[2 * p]));
        float hi = __builtin_amdgcn_rcpf(1.0f + __builtin_amdgcn_exp2f(-LOG2E * acc[2 * p + 1]));
        ushort ulo = __builtin_bit_cast(ushort, (__bf16)lo);
        ushort uhi = __builtin_bit_cast(ushort, (__bf16)hi);
        outp[p] = (uint)ulo | ((uint)uhi << 16);
    }
    uint4* dst = (uint4*)(e_out + (size_t)g * 24);
#pragma unroll
    for (int q = 0; q < 3; q++) dst[q] = ((const uint4*)outp)[q];
}

// ---------------- recurrent kernel: 128 blocks x 512 threads (8 waves), 8 rows/block.
// h-GEMM in INT8 (mfma_i32_16x16x64_i8, K=64): 8 MFMA/wave/step vs 16 bf16 —
// halves the MFMA-instruction floor identified in R3..R11 (interval ~= 40 instr/SIMD
// x ~40cyc in EVERY bf16 config). e-part stays bf16, hoisted off the critical path.
// z (=h) quantized to i8 at scale 1/127 (|h|<1); W per-unit-scaled i8.
// A=z(LDS i8), B=Wq(regs): D[m=row][n=unit], row=(lane>>4)*4+reg, unit=16wv+(lane&15)
// (C/D layout dtype-independent, verified). Compaction via permlane32_swap as R7
// (unit is lane-invariant under the swap since l15 matches across the 32-halves).
__global__ __launch_bounds__(512, 1) void lstm_kernel(
    const ushort* __restrict__ e_ws,
    const float* __restrict__ Wf, const float* __restrict__ bf_,
    const float* __restrict__ Wi, const float* __restrict__ bi_,
    const float* __restrict__ Wg, const float* __restrict__ bg_,
    const float* __restrict__ Wo, const float* __restrict__ bo_,
    const float* __restrict__ Wout, const float* __restrict__ bout,
    float* __restrict__ out) {
    // z-buf: i8 h, [P][ks2][kg4][row16][16B] = 4 KiB total (k = ks*64+kg*16+j = unit)
    __shared__ __align__(16) char zq[2][2][4][16][16];

    const int tid  = threadIdx.x;
    const int lane = tid & 63;
    const int wv   = tid >> 6;      // 0..7 -> unit tile [16wv,16wv+16)
    const int l15  = lane & 15;
    const int kg   = lane >> 4;     // 0..3
    const int r0   = blockIdx.x * ROWS;

    const float* Wp[4] = {Wf, Wi, Wg, Wo};
    const float gsc[4] = {LOG2E, LOG2E, 2.0f * LOG2E, LOG2E};
    const int ucol = wv * 16 + l15;   // this lane's unit (D n-index)

    // ---- h-part weights: per-(gate,unit) scaled int8, packed [gt][ks] as 16B
    int4v wq[4][2];
    float fct[4];                     // dequant factor = s_w/127 per gate
#pragma unroll
    for (int gt = 0; gt < 4; gt++) {
        float amax = 1e-20f;
        for (int k = 0; k < 128; k++)
            amax = fmaxf(amax, fabsf(Wp[gt][(24 + k) * NUNITS + ucol] * gsc[gt]));
        float isq = 127.0f / amax;
        fct[gt] = amax / (127.0f * 127.0f);   // s_w * s_z, s_z = 1/127
#pragma unroll
        for (int ks = 0; ks < 2; ks++) {
#pragma unroll
            for (int w = 0; w < 4; w++) {
                int word = 0;
#pragma unroll
                for (int b = 0; b < 4; b++) {
                    int k = ks * 64 + kg * 16 + w * 4 + b;
                    int q = (int)__builtin_rintf(Wp[gt][(24 + k) * NUNITS + ucol] * gsc[gt] * isq);
                    word |= (q & 255) << (8 * b);
                }
                wq[gt][ks][w] = word;
            }
        }
    }
    // ---- e-part weights (bf16, K slice 128..159 -> ref rows 0..23 + pad)
    bf16x8 wrege[4];
#pragma unroll
    for (int gt = 0; gt < 4; gt++) {
#pragma unroll
        for (int j = 0; j < 8; j++) {
            int k = 128 + kg * 8 + j;
            float v = (k < 152) ? Wp[gt][(k - 128) * NUNITS + ucol] : 0.0f;
            wrege[gt][j] = (__bf16)(v * gsc[gt]);
        }
    }
    const float* Bp[4] = {bf_, bi_, bg_, bo_};
    f32x4 bias[4];
#pragma unroll
    for (int gt = 0; gt < 4; gt++) {
        float bv = Bp[gt][ucol] * gsc[gt];
#pragma unroll
        for (int r = 0; r < 4; r++) bias[gt][r] = bv;
    }
    const int4v zeroi = {0, 0, 0, 0};

    // zero both z buffers (h0 = 0)
    for (int i = tid; i < 2 * 2 * 4 * 16 * 16 / 4; i += 512) ((int*)zq)[i] = 0;

    // LDS addrs: read A-frag (16B per lane), write 2 i8 cells
    const char* zrd = &zq[0][0][kg][l15][0];            // + P*2048 + ks*1024
    const int q2 = lane >> 4;
    const int row_c0 = ((q2 & 1) << 2) | ((q2 >> 1) << 1);   // [0,4,2,6][q2]
    char* zwr = &zq[0][ucol >> 6][(ucol >> 4) & 3][row_c0][ucol & 15];

    // ---- e prefetch ring, depth 2 (rows l15<8, kg<3)
    const ushort* elbase = e_ws + ((size_t)(r0 + (l15 & 7)) * 24 + kg * 8);
    const bool eload = (kg < 3) && (l15 < 8);
    bf16x8 e0, e1;
#pragma unroll
    for (int j = 0; j < 8; j++) { e0[j] = (__bf16)0.0f; e1[j] = (__bf16)0.0f; }
    if (eload) {
        e0 = *(const bf16x8*)(const void*)(elbase);
        e1 = *(const bf16x8*)(const void*)(elbase + 24576);
    }

    __syncthreads();

    float c0 = 0.0f, c1 = 0.0f;
    f32x4 eA[4], eB[4];   // hoisted e-acc (bias + W_e*e(t)) per gate
#pragma unroll
    for (int gt = 0; gt < 4; gt++)
        eA[gt] = __builtin_amdgcn_mfma_f32_16x16x32_bf16(e0, wrege[gt], bias[gt], 0, 0, 0);
    if (eload) e0 = *(const bf16x8*)(const void*)(elbase + 2 * 24576);

    auto STEP = [&](int t, int P, f32x4 (&cur)[4], f32x4 (&nxt)[4], bf16x8& enext) {
        const char* zb = zrd + P * 2048;
        int4v z0 = *(const int4v*)(const void*)(zb);          // ks=0 (units 0-63)
        int4v z1 = *(const int4v*)(const void*)(zb + 1024);   // ks=1 (units 64-127)

        // h-GEMM: 8 i8 MFMAs (2-deep chain per gate), i32 accumulate
        int4v acc[4];
#pragma unroll
        for (int gt = 0; gt < 4; gt++)
            acc[gt] = __builtin_amdgcn_mfma_i32_16x16x64_i8(z0, wq[gt][0], zeroi, 0, 0, 0);
#pragma unroll
        for (int gt = 0; gt < 4; gt++)
            acc[gt] = __builtin_amdgcn_mfma_i32_16x16x64_i8(z1, wq[gt][1], acc[gt], 0, 0, 0);

        // hoisted e-MFMAs for t+1 (bf16, independent of h)
#pragma unroll
        for (int gt = 0; gt < 4; gt++)
            nxt[gt] = __builtin_amdgcn_mfma_f32_16x16x32_bf16(enext, wrege[gt], bias[gt], 0, 0, 0);
        {
            int tf = t + 3; if (tf > T_STEPS - 1) tf = T_STEPS - 1;
            if (eload) enext = *(const bf16x8*)(const void*)(elbase + (size_t)tf * 24576);
        }

        // dequant + bias/e add, then compact (lanes0-31 rows{0,1}... as R7)
        float g0[4], g1[4];
#pragma unroll
        for (int gt = 0; gt < 4; gt++) {
            float p0 = fmaf((float)acc[gt][0], fct[gt], cur[gt][0]);
            float p1 = fmaf((float)acc[gt][1], fct[gt], cur[gt][1]);
            float p2 = fmaf((float)acc[gt][2], fct[gt], cur[gt][2]);
            float p3 = fmaf((float)acc[gt][3], fct[gt], cur[gt][3]);
            g0[gt] = swap_lo(p0, p2);
            g1[gt] = swap_lo(p1, p3);
        }

        float fg0 = sigm_pre(g0[0]), fg1 = sigm_pre(g1[0]);
        float ig0 = sigm_pre(g0[1]), ig1 = sigm_pre(g1[1]);
        float gg0 = tanh_pre(g0[2]), gg1 = tanh_pre(g1[2]);
        float og0 = sigm_pre(g0[3]), og1 = sigm_pre(g1[3]);
        c0 = fmaf(c0, fg0, ig0 * gg0);
        c1 = fmaf(c1, fg1, ig1 * gg1);
        float h0 = tanh_pre(2.0f * LOG2E * c0) * og0;
        float h1 = tanh_pre(2.0f * LOG2E * c1) * og1;

        // quantize h to i8 (|h|<1 strictly -> no clamp) and store 2 cells
        int q0i = (int)__builtin_rintf(h0 * 127.0f);
        int q1i = (int)__builtin_rintf(h1 * 127.0f);
        char* zw = zwr + (P ^ 1) * 2048;
        zw[0]  = (char)q0i;   // (row_c0,   unit)
        zw[16] = (char)q1i;   // (row_c0+1, unit)

        asm volatile("s_waitcnt lgkmcnt(0)" ::: "memory");
        __builtin_amdgcn_s_barrier();
        __builtin_amdgcn_sched_barrier(0);
    };

    for (int t = 0; t < T_STEPS; t += 2) {
        STEP(t,     0, eA, eB, e1);
        STEP(t + 1, 1, eB, eA, e0);
    }

    // h_last (i8) is in buffer 0
    if (tid < ROWS) {
        float s2 = 0.0f;
#pragma unroll
        for (int k = 0; k < NUNITS; k++)
            s2 += (float)zq[0][k >> 6][(k >> 4) & 3][tid][k & 15] * Wout[k];
        float s = s2 * (1.0f / 127.0f) + bout[0];
        out[r0 + tid] = __builtin_amdgcn_rcpf(1.0f + __builtin_amdgcn_exp2f(-LOG2E * s));
    }
}

extern "C" void kernel_launch(void* const* d_in, const int* in_sizes, int n_in,
                              void* d_out, int out_size, void* d_ws, size_t ws_size,
                              hipStream_t stream) {
    const float* x     = (const float*)d_in[0];
    const float* Wemb  = (const float*)d_in[1];
    const float* bemb  = (const float*)d_in[2];
    const float* Wf    = (const float*)d_in[3];
    const float* bf_   = (const float*)d_in[4];
    const float* Wi    = (const float*)d_in[5];
    const float* bi_   = (const float*)d_in[6];
    const float* Wg    = (const float*)d_in[7];
    const float* bg_   = (const float*)d_in[8];
    const float* Wo    = (const float*)d_in[9];
    const float* bo_   = (const float*)d_in[10];
    const float* Wout  = (const float*)d_in[11];
    const float* bout  = (const float*)d_in[12];
    float* out = (float*)d_out;
    ushort* e_ws = (ushort*)d_ws;   // [T][B][24] bf16, ~96 MB

    int nrows = BATCH * T_STEPS;
    emb_kernel<<<nrows / 256, 256, 0, stream>>>(x, Wemb, bemb, e_ws);
    lstm_kernel<<<BATCH / ROWS, 512, 0, stream>>>(e_ws, Wf, bf_, Wi, bi_, Wg, bg_,
                                                  Wo, bo_, Wout, bout, out);
}

// Round 13
// 1422.911 us; speedup vs baseline: 3.9358x; 1.0830x over previous
//
#include <hip/hip_runtime.h>
#include <hip/hip_bf16.h>

#define T_STEPS 2048
#define BATCH   1024
#define NUNITS  128
#define ROWS    4
#define LOG2E   1.4426950408889634f

typedef __attribute__((ext_vector_type(4))) float  f32x4;
typedef __attribute__((ext_vector_type(2))) int    i32x2;
typedef __attribute__((ext_vector_type(4))) int    int4v;

__device__ __forceinline__ float sigm_pre(float xs) {
    return __builtin_amdgcn_rcpf(1.0f + __builtin_amdgcn_exp2f(-xs));
}
__device__ __forceinline__ float tanh_pre(float xs) {
    return fmaf(-2.0f, __builtin_amdgcn_rcpf(1.0f + __builtin_amdgcn_exp2f(xs)), 1.0f);
}
// lanes 0-31 = a[self], lanes 32-63 = b[lane-32]  (verified R7); int version
__device__ __forceinline__ int swap_lo_i(int a, int b) {
    i32x2 r = __builtin_amdgcn_permlane32_swap(a, b, false, false);
    return r[0];
}

// ---------------- embedding pre-pass: e[t][b][0..23] = rint(sigmoid(.)*127) as i8,
// bytes 24-31 zero pad (32B row so the lstm kernel's kg*16 slices stay in-row)
__global__ __launch_bounds__(256) void emb_kernel(const float* __restrict__ x,
                                                  const float* __restrict__ Wemb,
                                                  const float* __restrict__ bemb,
                                                  uchar* __restrict__ e_out) {
    int g = blockIdx.x * 256 + threadIdx.x;   // g = t*1024 + b
    int t = g >> 10;
    int b = g & 1023;
    const float* xr = x + ((size_t)b * T_STEPS + t) * 64;

    float4 xv[16];
#pragma unroll
    for (int i = 0; i < 16; i++) xv[i] = ((const float4*)xr)[i];

    float acc[24];
#pragma unroll
    for (int j = 0; j < 24; j++) acc[j] = bemb[j];

#pragma unroll
    for (int d = 0; d < 64; d++) {
        float xs = ((const float*)xv)[d];
#pragma unroll
        for (int j = 0; j < 24; j++) acc[j] = fmaf(xs, Wemb[d * 24 + j], acc[j]);
    }

    uint outp[8] = {0, 0, 0, 0, 0, 0, 0, 0};
#pragma unroll
    for (int j = 0; j < 24; j++) {
        float s = __builtin_amdgcn_rcpf(1.0f + __builtin_amdgcn_exp2f(-LOG2E * acc[j]));
        int q = (int)__builtin_rintf(s * 127.0f);
        outp[j >> 2] |= (uint)(q & 255) << (8 * (j & 3));
    }
    uint4* dst = (uint4*)(e_out + (size_t)g * 32);
    dst[0] = ((const uint4*)outp)[0];
    dst[1] = ((const uint4*)outp)[1];
}

// ---------------- recurrent kernel: 256 blocks x 512 threads (8 waves), 4 rows/block.
// FULL chip (256 CUs), per-CU demand halved vs R12 (R11/R12 finding: interval =
// sum of comparable per-CU throughput terms, no single dominant phase).
// All-INT8 GEMM, K=192 = [h(128) | e(24) | pad]: 12 mfma_i32_16x16x64_i8 per wave.
// A=z(i8: LDS for k<128, regs for e-slice), B=Wq(regs, per-(gate,unit) scale).
// D[m=row][n=unit]; valid rows 0-3 on kg=0 lanes; i32 compaction via
// permlane32_swap (lanes0-15 rows{0,1}, lanes32-47 rows{2,3}), then dequant+bias.
__global__ __launch_bounds__(512, 1) void lstm_kernel(
    const uchar* __restrict__ e_ws,
    const float* __restrict__ Wf, const float* __restrict__ bf_,
    const float* __restrict__ Wi, const float* __restrict__ bi_,
    const float* __restrict__ Wg, const float* __restrict__ bg_,
    const float* __restrict__ Wo, const float* __restrict__ bo_,
    const float* __restrict__ Wout, const float* __restrict__ bout,
    float* __restrict__ out) {
    __shared__ __align__(16) char zq[2][2][4][16][16];   // [P][ks2][kg4][row16][16B] = 4 KiB

    const int tid  = threadIdx.x;
    const int lane = tid & 63;
    const int wv   = tid >> 6;      // 0..7 -> unit tile [16wv,16wv+16)
    const int l15  = lane & 15;
    const int kg   = lane >> 4;     // 0..3
    const int r0   = blockIdx.x * ROWS;

    const float* Wp[4] = {Wf, Wi, Wg, Wo};
    const float* Bp[4] = {bf_, bi_, bg_, bo_};
    const float gsc[4] = {LOG2E, LOG2E, 2.0f * LOG2E, LOG2E};
    const int ucol = wv * 16 + l15;   // this lane's unit (D n-index)

    // ---- weights: per-(gate,unit) scaled int8 over ALL 152 K-rows, packed [gt][ks3]
    int4v wq[4][3];
    float fct[4], biasv[4];
#pragma unroll
    for (int gt = 0; gt < 4; gt++) {
        float amax = 1e-20f;
        for (int k = 0; k < 152; k++) {
            float v = (k < 128) ? Wp[gt][(24 + k) * NUNITS + ucol]
                                : Wp[gt][(k - 128) * NUNITS + ucol];
            amax = fmaxf(amax, fabsf(v * gsc[gt]));
        }
        float isq = 127.0f / amax;
        fct[gt] = amax * (1.0f / 16129.0f);   // s_w/127: i32 -> pre-activation scale
#pragma unroll
        for (int ks = 0; ks < 3; ks++) {
#pragma unroll
            for (int w = 0; w < 4; w++) {
                int word = 0;
#pragma unroll
                for (int b = 0; b < 4; b++) {
                    int k = ks * 64 + kg * 16 + w * 4 + b;
                    float v = 0.0f;
                    if (k < 128) v = Wp[gt][(24 + k) * NUNITS + ucol] * gsc[gt];
                    else if (k < 152) v = Wp[gt][(k - 128) * NUNITS + ucol] * gsc[gt];
                    int q = (int)__builtin_rintf(v * isq);
                    word |= (q & 255) << (8 * b);
                }
                wq[gt][ks][w] = word;
            }
        }
        biasv[gt] = Bp[gt][ucol] * gsc[gt];
    }
    const int4v zeroi = {0, 0, 0, 0};

    // zero both z buffers (h0 = 0; rows 4-15 hold garbage cells, never consumed)
    for (int i = tid; i < (int)(sizeof(zq) / 4); i += 512) ((int*)zq)[i] = 0;

    // LDS addrs: A-frag read 16B (k = ks*64 + kg*16 + j), write 2 i8 cells
    const char* zrd = &zq[0][0][kg][l15][0];            // + P*2048 + ks*1024
    const int q2 = lane >> 4;
    const int row_c0 = ((q2 & 1) << 2) | ((q2 >> 1) << 1);   // [0,4,2,6][q2]
    char* zwr = &zq[0][ucol >> 6][(ucol >> 4) & 3][row_c0][ucol & 15];

    // ---- e ring, depth 2: lanes (kg<2, l15<4) hold row l15, bytes kg*16..+16
    const uchar* elbase = e_ws + ((size_t)(r0 + (l15 & 3)) * 32 + kg * 16);
    const bool eload = (kg < 2) && (l15 < 4);
    int4v e0 = zeroi, e1 = zeroi;
    if (eload) {
        e0 = *(const int4v*)(const void*)(elbase);
        e1 = *(const int4v*)(const void*)(elbase + 32768);   // t=1 (1024*32 B/step)
    }

    __syncthreads();

    float c0 = 0.0f, c1 = 0.0f;

    auto STEP = [&](int t, int P, int4v& ecur) {
        // e-slice MFMA first: register A-operand, overlaps the z ds_read latency
        int4v acc[4];
#pragma unroll
        for (int gt = 0; gt < 4; gt++)
            acc[gt] = __builtin_amdgcn_mfma_i32_16x16x64_i8(ecur, wq[gt][2], zeroi, 0, 0, 0);

        const char* zb = zrd + P * 2048;
        int4v z0 = *(const int4v*)(const void*)(zb);          // k 0-63
        int4v z1 = *(const int4v*)(const void*)(zb + 1024);   // k 64-127
#pragma unroll
        for (int gt = 0; gt < 4; gt++)
            acc[gt] = __builtin_amdgcn_mfma_i32_16x16x64_i8(z0, wq[gt][0], acc[gt], 0, 0, 0);
#pragma unroll
        for (int gt = 0; gt < 4; gt++)
            acc[gt] = __builtin_amdgcn_mfma_i32_16x16x64_i8(z1, wq[gt][1], acc[gt], 0, 0, 0);

        // refill ering with e(t+2) (consumed 2 intervals later; HBM latency covered)
        {
            int tf = t + 2; if (tf > T_STEPS - 1) tf = T_STEPS - 1;
            if (eload) ecur = *(const int4v*)(const void*)(elbase + (size_t)tf * 32768);
        }

        // compact i32 acc (bit-exact), then dequant + bias
        float g0[4], g1[4];
#pragma unroll
        for (int gt = 0; gt < 4; gt++) {
            int a0 = swap_lo_i(acc[gt][0], acc[gt][2]);
            int a1 = swap_lo_i(acc[gt][1], acc[gt][3]);
            g0[gt] = fmaf((float)a0, fct[gt], biasv[gt]);
            g1[gt] = fmaf((float)a1, fct[gt], biasv[gt]);
        }

        float fg0 = sigm_pre(g0[0]), fg1 = sigm_pre(g1[0]);
        float ig0 = sigm_pre(g0[1]), ig1 = sigm_pre(g1[1]);
        float gg0 = tanh_pre(g0[2]), gg1 = tanh_pre(g1[2]);
        float og0 = sigm_pre(g0[3]), og1 = sigm_pre(g1[3]);
        c0 = fmaf(c0, fg0, ig0 * gg0);
        c1 = fmaf(c1, fg1, ig1 * gg1);
        float h0 = tanh_pre(2.0f * LOG2E * c0) * og0;
        float h1 = tanh_pre(2.0f * LOG2E * c1) * og1;

        // quantize h (|h|<1 strictly) and store 2 i8 cells
        int q0i = (int)__builtin_rintf(h0 * 127.0f);
        int q1i = (int)__builtin_rintf(h1 * 127.0f);
        char* zw = zwr + (P ^ 1) * 2048;
        zw[0]  = (char)q0i;   // (row_c0,   unit)
        zw[16] = (char)q1i;   // (row_c0+1, unit)

        asm volatile("s_waitcnt lgkmcnt(0)" ::: "memory");
        __builtin_amdgcn_s_barrier();
        __builtin_amdgcn_sched_barrier(0);
    };

    for (int t = 0; t < T_STEPS; t += 2) {
        STEP(t,     0, e0);
        STEP(t + 1, 1, e1);
    }

    // h_last (i8) in buffer 0, rows 0-3
    if (tid < ROWS) {
        float s2 = 0.0f;
#pragma unroll
        for (int k = 0; k < NUNITS; k++)
            s2 += (float)zq[0][k >> 6][(k >> 4) & 3][tid][k & 15] * Wout[k];
        float s = s2 * (1.0f / 127.0f) + bout[0];
        out[r0 + tid] = __builtin_amdgcn_rcpf(1.0f + __builtin_amdgcn_exp2f(-LOG2E * s));
    }
}

extern "C" void kernel_launch(void* const* d_in, const int* in_sizes, int n_in,
                              void* d_out, int out_size, void* d_ws, size_t ws_size,
                              hipStream_t stream) {
    const float* x     = (const float*)d_in[0];
    const float* Wemb  = (const float*)d_in[1];
    const float* bemb  = (const float*)d_in[2];
    const float* Wf    = (const float*)d_in[3];
    const float* bf_   = (const float*)d_in[4];
    const float* Wi    = (const float*)d_in[5];
    const float* bi_   = (const float*)d_in[6];
    const float* Wg    = (const float*)d_in[7];
    const float* bg_   = (const float*)d_in[8];
    const float* Wo    = (const float*)d_in[9];
    const float* bo_   = (const float*)d_in[10];
    const float* Wout  = (const float*)d_in[11];
    const float* bout  = (const float*)d_in[12];
    float* out = (float*)d_out;
    uchar* e_ws = (uchar*)d_ws;   // [T][B][32] i8, 64 MB

    int nrows = BATCH * T_STEPS;
    emb_kernel<<<nrows / 256, 256, 0, stream>>>(x, Wemb, bemb, e_ws);
    lstm_kernel<<<BATCH / ROWS, 512, 0, stream>>>(e_ws, Wf, bf_, Wi, bi_, Wg, bg_,
                                                  Wo, bo_, Wout, bout, out);
}

// Round 14
// 1252.620 us; speedup vs baseline: 4.4708x; 1.1359x over previous
//
#include <hip/hip_runtime.h>
#include <hip/hip_bf16.h>

#define T_STEPS 2048
#define BATCH   1024
#define NUNITS  128
#define ROWS    4
#define LOG2E   1.4426950408889634f

typedef __attribute__((ext_vector_type(4))) float  f32x4;
typedef __attribute__((ext_vector_type(2))) int    i32x2;
typedef __attribute__((ext_vector_type(4))) int    int4v;

__device__ __forceinline__ float sigm_pre(float xs) {
    return __builtin_amdgcn_rcpf(1.0f + __builtin_amdgcn_exp2f(-xs));
}
__device__ __forceinline__ float tanh_pre(float xs) {
    return fmaf(-2.0f, __builtin_amdgcn_rcpf(1.0f + __builtin_amdgcn_exp2f(xs)), 1.0f);
}
// lanes 0-31 = a[self], lanes 32-63 = b[lane-32]  (verified R7); int version
__device__ __forceinline__ int swap_lo_i(int a, int b) {
    i32x2 r = __builtin_amdgcn_permlane32_swap(a, b, false, false);
    return r[0];
}

// ---------------- embedding pre-pass: e[t][b][0..23] = rint(sigmoid(.)*127) as i8,
// bytes 24-31 zero pad (verified R13)
__global__ __launch_bounds__(256) void emb_kernel(const float* __restrict__ x,
                                                  const float* __restrict__ Wemb,
                                                  const float* __restrict__ bemb,
                                                  uchar* __restrict__ e_out) {
    int g = blockIdx.x * 256 + threadIdx.x;   // g = t*1024 + b
    int t = g >> 10;
    int b = g & 1023;
    const float* xr = x + ((size_t)b * T_STEPS + t) * 64;

    float4 xv[16];
#pragma unroll
    for (int i = 0; i < 16; i++) xv[i] = ((const float4*)xr)[i];

    float acc[24];
#pragma unroll
    for (int j = 0; j < 24; j++) acc[j] = bemb[j];

#pragma unroll
    for (int d = 0; d < 64; d++) {
        float xs = ((const float*)xv)[d];
#pragma unroll
        for (int j = 0; j < 24; j++) acc[j] = fmaf(xs, Wemb[d * 24 + j], acc[j]);
    }

    uint outp[8] = {0, 0, 0, 0, 0, 0, 0, 0};
#pragma unroll
    for (int j = 0; j < 24; j++) {
        float s = __builtin_amdgcn_rcpf(1.0f + __builtin_amdgcn_exp2f(-LOG2E * acc[j]));
        int q = (int)__builtin_rintf(s * 127.0f);
        outp[j >> 2] |= (uint)(q & 255) << (8 * (j & 3));
    }
    uint4* dst = (uint4*)(e_out + (size_t)g * 32);
    dst[0] = ((const uint4*)outp)[0];
    dst[1] = ((const uint4*)outp)[1];
}

// ---------------- recurrent kernel: 256 blocks x 512 threads (8 waves), 4 rows/block.
// All-INT8 GEMM (verified R13). NEW vs R13: full cell distribution — after the
// permlane32_swap pair, one ds_swizzle(xor16) + select gives lane-group kg
// exactly row kg of its unit: 1 valid cell/thread, zero garbage VALU
// (R13 post-mortem: half of all gate math was computing discarded rows 4-7).
__global__ __launch_bounds__(512, 1) void lstm_kernel(
    const uchar* __restrict__ e_ws,
    const float* __restrict__ Wf, const float* __restrict__ bf_,
    const float* __restrict__ Wi, const float* __restrict__ bi_,
    const float* __restrict__ Wg, const float* __restrict__ bg_,
    const float* __restrict__ Wo, const float* __restrict__ bo_,
    const float* __restrict__ Wout, const float* __restrict__ bout,
    float* __restrict__ out) {
    __shared__ __align__(16) char zq[2][2][4][16][16];   // [P][ks2][kg4][row16][16B] = 4 KiB

    const int tid  = threadIdx.x;
    const int lane = tid & 63;
    const int wv   = tid >> 6;      // 0..7 -> unit tile [16wv,16wv+16)
    const int l15  = lane & 15;
    const int kg   = lane >> 4;     // 0..3 (A k-group; also this thread's OWNED ROW)
    const int r0   = blockIdx.x * ROWS;

    const float* Wp[4] = {Wf, Wi, Wg, Wo};
    const float* Bp[4] = {bf_, bi_, bg_, bo_};
    const float gsc[4] = {LOG2E, LOG2E, 2.0f * LOG2E, LOG2E};
    const int ucol = wv * 16 + l15;   // this lane's unit (D n-index)

    // ---- weights: per-(gate,unit) scaled int8 over all 152 K-rows, packed [gt][ks3]
    int4v wq[4][3];
    float fct[4], biasv[4];
#pragma unroll
    for (int gt = 0; gt < 4; gt++) {
        float amax = 1e-20f;
        for (int k = 0; k < 152; k++) {
            float v = (k < 128) ? Wp[gt][(24 + k) * NUNITS + ucol]
                                : Wp[gt][(k - 128) * NUNITS + ucol];
            amax = fmaxf(amax, fabsf(v * gsc[gt]));
        }
        float isq = 127.0f / amax;
        fct[gt] = amax * (1.0f / 16129.0f);   // s_w/127: i32 -> pre-activation scale
#pragma unroll
        for (int ks = 0; ks < 3; ks++) {
#pragma unroll
            for (int w = 0; w < 4; w++) {
                int word = 0;
#pragma unroll
                for (int b = 0; b < 4; b++) {
                    int k = ks * 64 + kg * 16 + w * 4 + b;
                    float v = 0.0f;
                    if (k < 128) v = Wp[gt][(24 + k) * NUNITS + ucol] * gsc[gt];
                    else if (k < 152) v = Wp[gt][(k - 128) * NUNITS + ucol] * gsc[gt];
                    int q = (int)__builtin_rintf(v * isq);
                    word |= (q & 255) << (8 * b);
                }
                wq[gt][ks][w] = word;
            }
        }
        biasv[gt] = Bp[gt][ucol] * gsc[gt];
    }
    const int4v zeroi = {0, 0, 0, 0};

    // zero both z buffers (h0 = 0; rows 4-15 stay zero forever)
    for (int i = tid; i < (int)(sizeof(zq) / 4); i += 512) ((int*)zq)[i] = 0;

    // LDS addrs: A-frag read 16B (k = ks*64 + kg*16 + j); write 1 i8 cell (row=kg)
    const char* zrd = &zq[0][0][kg][l15][0];            // + P*2048 + ks*1024
    char* zwr = &zq[0][ucol >> 6][(ucol >> 4) & 3][kg][ucol & 15];

    // ---- e ring, depth 2: lanes (kg<2, l15<4) hold row l15, bytes kg*16..+16
    const uchar* elbase = e_ws + ((size_t)(r0 + (l15 & 3)) * 32 + kg * 16);
    const bool eload = (kg < 2) && (l15 < 4);
    int4v e0 = zeroi, e1 = zeroi;
    if (eload) {
        e0 = *(const int4v*)(const void*)(elbase);
        e1 = *(const int4v*)(const void*)(elbase + 32768);   // t=1 (1024*32 B/step)
    }

    __syncthreads();

    float c0 = 0.0f;

    auto STEP = [&](int t, int P, int4v& ecur) {
        // e-slice MFMA first: register A-operand, overlaps the z ds_read latency
        int4v acc[4];
#pragma unroll
        for (int gt = 0; gt < 4; gt++)
            acc[gt] = __builtin_amdgcn_mfma_i32_16x16x64_i8(ecur, wq[gt][2], zeroi, 0, 0, 0);

        const char* zb = zrd + P * 2048;
        int4v z0 = *(const int4v*)(const void*)(zb);          // k 0-63
        int4v z1 = *(const int4v*)(const void*)(zb + 1024);   // k 64-127
#pragma unroll
        for (int gt = 0; gt < 4; gt++)
            acc[gt] = __builtin_amdgcn_mfma_i32_16x16x64_i8(z0, wq[gt][0], acc[gt], 0, 0, 0);
#pragma unroll
        for (int gt = 0; gt < 4; gt++)
            acc[gt] = __builtin_amdgcn_mfma_i32_16x16x64_i8(z1, wq[gt][1], acc[gt], 0, 0, 0);

        // refill ering with e(t+2)
        {
            int tf = t + 2; if (tf > T_STEPS - 1) tf = T_STEPS - 1;
            if (eload) ecur = *(const int4v*)(const void*)(elbase + (size_t)tf * 32768);
        }

        // full compaction (i32, bit-exact): swap pair puts rows{0,1}->lanes0-15,
        // rows{2,3}->lanes32-47; ds_swizzle xor16 + select moves the odd row to
        // lane-groups 1 and 3 -> lane-group kg owns row kg of unit ucol.
        float g[4];
#pragma unroll
        for (int gt = 0; gt < 4; gt++) {
            int a0 = swap_lo_i(acc[gt][0], acc[gt][2]);   // lanes0-15 r0, 32-47 r2
            int a1 = swap_lo_i(acc[gt][1], acc[gt][3]);   // lanes0-15 r1, 32-47 r3
            int a1s = __builtin_amdgcn_ds_swizzle(a1, 0x401F);   // lane ^= 16
            int sel = (lane & 16) ? a1s : a0;
            g[gt] = fmaf((float)sel, fct[gt], biasv[gt]);
        }

        float fg = sigm_pre(g[0]);
        float ig = sigm_pre(g[1]);
        float gg = tanh_pre(g[2]);
        float og = sigm_pre(g[3]);
        c0 = fmaf(c0, fg, ig * gg);
        float h0 = tanh_pre(2.0f * LOG2E * c0) * og;

        // quantize h (|h|<1 strictly); every lane writes its 1 cell (row kg)
        int q0i = (int)__builtin_rintf(h0 * 127.0f);
        *(zwr + ((P ^ 1) * 2048)) = (char)q0i;

        asm volatile("s_waitcnt lgkmcnt(0)" ::: "memory");
        __builtin_amdgcn_s_barrier();
        __builtin_amdgcn_sched_barrier(0);
    };

    for (int t = 0; t < T_STEPS; t += 2) {
        STEP(t,     0, e0);
        STEP(t + 1, 1, e1);
    }

    // h_last (i8) in buffer 0, rows 0-3
    if (tid < ROWS) {
        float s2 = 0.0f;
#pragma unroll
        for (int k = 0; k < NUNITS; k++)
            s2 += (float)zq[0][k >> 6][(k >> 4) & 3][tid][k & 15] * Wout[k];
        float s = s2 * (1.0f / 127.0f) + bout[0];
        out[r0 + tid] = __builtin_amdgcn_rcpf(1.0f + __builtin_amdgcn_exp2f(-LOG2E * s));
    }
}

extern "C" void kernel_launch(void* const* d_in, const int* in_sizes, int n_in,
                              void* d_out, int out_size, void* d_ws, size_t ws_size,
                              hipStream_t stream) {
    const float* x     = (const float*)d_in[0];
    const float* Wemb  = (const float*)d_in[1];
    const float* bemb  = (const float*)d_in[2];
    const float* Wf    = (const float*)d_in[3];
    const float* bf_   = (const float*)d_in[4];
    const float* Wi    = (const float*)d_in[5];
    const float* bi_   = (const float*)d_in[6];
    const float* Wg    = (const float*)d_in[7];
    const float* bg_   = (const float*)d_in[8];
    const float* Wo    = (const float*)d_in[9];
    const float* bo_   = (const float*)d_in[10];
    const float* Wout  = (const float*)d_in[11];
    const float* bout  = (const float*)d_in[12];
    float* out = (float*)d_out;
    uchar* e_ws = (uchar*)d_ws;   // [T][B][32] i8, 64 MB

    int nrows = BATCH * T_STEPS;
    emb_kernel<<<nrows / 256, 256, 0, stream>>>(x, Wemb, bemb, e_ws);
    lstm_kernel<<<BATCH / ROWS, 512, 0, stream>>>(e_ws, Wf, bf_, Wi, bi_, Wg, bg_,
                                                  Wo, bo_, Wout, bout, out);
}

// Round 15
// 1214.205 us; speedup vs baseline: 4.6123x; 1.0316x over previous
//
#include <hip/hip_runtime.h>
#include <hip/hip_bf16.h>

#define T_STEPS 2048
#define BATCH   1024
#define NUNITS  128
#define ROWS    4
#define LOG2E   1.4426950408889634f

typedef __attribute__((ext_vector_type(4))) float  f32x4;
typedef __attribute__((ext_vector_type(2))) int    i32x2;
typedef __attribute__((ext_vector_type(4))) int    int4v;

__device__ __forceinline__ float sigm_pre(float xs) {
    return __builtin_amdgcn_rcpf(1.0f + __builtin_amdgcn_exp2f(-xs));
}
__device__ __forceinline__ float tanh_pre(float xs) {
    return fmaf(-2.0f, __builtin_amdgcn_rcpf(1.0f + __builtin_amdgcn_exp2f(xs)), 1.0f);
}
// lanes 0-31 = a[self], lanes 32-63 = b[lane-32]  (verified R7); int version
__device__ __forceinline__ int swap_lo_i(int a, int b) {
    i32x2 r = __builtin_amdgcn_permlane32_swap(a, b, false, false);
    return r[0];
}
// 16-lane-granular analog: ret lanes with (lane&16)==0 = a[self], ==1 = b[lane-16]
__device__ __forceinline__ int swap16_lo_i(int a, int b) {
    i32x2 r = __builtin_amdgcn_permlane16_swap(a, b, false, false);
    return r[0];
}

// ---------------- embedding pre-pass: e[t][b][0..23] = rint(sigmoid(.)*127) as i8,
// bytes 24-31 zero pad (verified R13)
__global__ __launch_bounds__(256) void emb_kernel(const float* __restrict__ x,
                                                  const float* __restrict__ Wemb,
                                                  const float* __restrict__ bemb,
                                                  uchar* __restrict__ e_out) {
    int g = blockIdx.x * 256 + threadIdx.x;   // g = t*1024 + b
    int t = g >> 10;
    int b = g & 1023;
    const float* xr = x + ((size_t)b * T_STEPS + t) * 64;

    float4 xv[16];
#pragma unroll
    for (int i = 0; i < 16; i++) xv[i] = ((const float4*)xr)[i];

    float acc[24];
#pragma unroll
    for (int j = 0; j < 24; j++) acc[j] = bemb[j];

#pragma unroll
    for (int d = 0; d < 64; d++) {
        float xs = ((const float*)xv)[d];
#pragma unroll
        for (int j = 0; j < 24; j++) acc[j] = fmaf(xs, Wemb[d * 24 + j], acc[j]);
    }

    uint outp[8] = {0, 0, 0, 0, 0, 0, 0, 0};
#pragma unroll
    for (int j = 0; j < 24; j++) {
        float s = __builtin_amdgcn_rcpf(1.0f + __builtin_amdgcn_exp2f(-LOG2E * acc[j]));
        int q = (int)__builtin_rintf(s * 127.0f);
        outp[j >> 2] |= (uint)(q & 255) << (8 * (j & 3));
    }
    uint4* dst = (uint4*)(e_out + (size_t)g * 32);
    dst[0] = ((const uint4*)outp)[0];
    dst[1] = ((const uint4*)outp)[1];
}

// ---------------- recurrent kernel: 256 blocks x 512 threads (8 waves), 4 rows/block.
// All-INT8 GEMM, 1 valid cell/thread (verified R14). NEW vs R14:
//  (a) compaction last stage = v_permlane16_swap (VALU pipe) instead of
//      ds_swizzle+cndmask (LDS pipe was the convoyed resource: 32 ops/CU-step);
//  (b) e prefetch = marching pointer, no per-step clamp (reads overrun into the
//      >=96MB workspace by <=2 steps; overrun values are never consumed).
__global__ __launch_bounds__(512, 1) void lstm_kernel(
    const uchar* __restrict__ e_ws,
    const float* __restrict__ Wf, const float* __restrict__ bf_,
    const float* __restrict__ Wi, const float* __restrict__ bi_,
    const float* __restrict__ Wg, const float* __restrict__ bg_,
    const float* __restrict__ Wo, const float* __restrict__ bo_,
    const float* __restrict__ Wout, const float* __restrict__ bout,
    float* __restrict__ out) {
    __shared__ __align__(16) char zq[2][2][4][16][16];   // [P][ks2][kg4][row16][16B] = 4 KiB

    const int tid  = threadIdx.x;
    const int lane = tid & 63;
    const int wv   = tid >> 6;      // 0..7 -> unit tile [16wv,16wv+16)
    const int l15  = lane & 15;
    const int kg   = lane >> 4;     // 0..3 (A k-group; also this thread's OWNED ROW)
    const int r0   = blockIdx.x * ROWS;

    const float* Wp[4] = {Wf, Wi, Wg, Wo};
    const float* Bp[4] = {bf_, bi_, bg_, bo_};
    const float gsc[4] = {LOG2E, LOG2E, 2.0f * LOG2E, LOG2E};
    const int ucol = wv * 16 + l15;   // this lane's unit (D n-index)

    // ---- weights: per-(gate,unit) scaled int8 over all 152 K-rows, packed [gt][ks3]
    int4v wq[4][3];
    float fct[4], biasv[4];
#pragma unroll
    for (int gt = 0; gt < 4; gt++) {
        float amax = 1e-20f;
        for (int k = 0; k < 152; k++) {
            float v = (k < 128) ? Wp[gt][(24 + k) * NUNITS + ucol]
                                : Wp[gt][(k - 128) * NUNITS + ucol];
            amax = fmaxf(amax, fabsf(v * gsc[gt]));
        }
        float isq = 127.0f / amax;
        fct[gt] = amax * (1.0f / 16129.0f);   // s_w/127: i32 -> pre-activation scale
#pragma unroll
        for (int ks = 0; ks < 3; ks++) {
#pragma unroll
            for (int w = 0; w < 4; w++) {
                int word = 0;
#pragma unroll
                for (int b = 0; b < 4; b++) {
                    int k = ks * 64 + kg * 16 + w * 4 + b;
                    float v = 0.0f;
                    if (k < 128) v = Wp[gt][(24 + k) * NUNITS + ucol] * gsc[gt];
                    else if (k < 152) v = Wp[gt][(k - 128) * NUNITS + ucol] * gsc[gt];
                    int q = (int)__builtin_rintf(v * isq);
                    word |= (q & 255) << (8 * b);
                }
                wq[gt][ks][w] = word;
            }
        }
        biasv[gt] = Bp[gt][ucol] * gsc[gt];
    }
    const int4v zeroi = {0, 0, 0, 0};

    // zero both z buffers (h0 = 0; rows 4-15 stay zero forever)
    for (int i = tid; i < (int)(sizeof(zq) / 4); i += 512) ((int*)zq)[i] = 0;

    // LDS addrs: A-frag read 16B (k = ks*64 + kg*16 + j); write 1 i8 cell (row=kg)
    const char* zrd = &zq[0][0][kg][l15][0];            // + P*2048 + ks*1024
    char* zwr = &zq[0][ucol >> 6][(ucol >> 4) & 3][kg][ucol & 15];

    // ---- e ring, depth 2: lanes (kg<2, l15<4) hold row l15, bytes kg*16..+16
    const uchar* elbase = e_ws + ((size_t)(r0 + (l15 & 3)) * 32 + kg * 16);
    const bool eload = (kg < 2) && (l15 < 4);
    int4v e0 = zeroi, e1 = zeroi;
    if (eload) {
        e0 = *(const int4v*)(const void*)(elbase);
        e1 = *(const int4v*)(const void*)(elbase + 32768);   // t=1 (1024*32 B/step)
    }
    const uchar* eptr = elbase + 2 * 32768;   // marching prefetch ptr: next load = e(2)

    __syncthreads();

    float c0 = 0.0f;

    auto STEP = [&](int P, int4v& ecur) {
        // e-slice MFMA first: register A-operand, overlaps the z ds_read latency
        int4v acc[4];
#pragma unroll
        for (int gt = 0; gt < 4; gt++)
            acc[gt] = __builtin_amdgcn_mfma_i32_16x16x64_i8(ecur, wq[gt][2], zeroi, 0, 0, 0);

        const char* zb = zrd + P * 2048;
        int4v z0 = *(const int4v*)(const void*)(zb);          // k 0-63
        int4v z1 = *(const int4v*)(const void*)(zb + 1024);   // k 64-127
#pragma unroll
        for (int gt = 0; gt < 4; gt++)
            acc[gt] = __builtin_amdgcn_mfma_i32_16x16x64_i8(z0, wq[gt][0], acc[gt], 0, 0, 0);
#pragma unroll
        for (int gt = 0; gt < 4; gt++)
            acc[gt] = __builtin_amdgcn_mfma_i32_16x16x64_i8(z1, wq[gt][1], acc[gt], 0, 0, 0);

        // refill ering with e(t+2): unconditional marching pointer (<=2-step overrun
        // into the >=96MB workspace; overrun loads never consumed)
        if (eload) ecur = *(const int4v*)(const void*)(eptr);
        eptr += 32768;

        // full compaction (i32, bit-exact, all-VALU): swap32 pair then swap16 ->
        // lane-group kg owns row kg of unit ucol
        float g[4];
#pragma unroll
        for (int gt = 0; gt < 4; gt++) {
            int a0 = swap_lo_i(acc[gt][0], acc[gt][2]);    // l0-15:r0, l32-47:r2
            int a1 = swap_lo_i(acc[gt][1], acc[gt][3]);    // l0-15:r1, l32-47:r3
            int sel = swap16_lo_i(a0, a1);                 // lane-group kg -> row kg
            g[gt] = fmaf((float)sel, fct[gt], biasv[gt]);
        }

        float fg = sigm_pre(g[0]);
        float ig = sigm_pre(g[1]);
        float gg = tanh_pre(g[2]);
        float og = sigm_pre(g[3]);
        c0 = fmaf(c0, fg, ig * gg);
        float h0 = tanh_pre(2.0f * LOG2E * c0) * og;

        // quantize h (|h|<1 strictly); every lane writes its 1 cell (row kg)
        int q0i = (int)__builtin_rintf(h0 * 127.0f);
        *(zwr + ((P ^ 1) * 2048)) = (char)q0i;

        asm volatile("s_waitcnt lgkmcnt(0)" ::: "memory");
        __builtin_amdgcn_s_barrier();
        __builtin_amdgcn_sched_barrier(0);
    };

    for (int t = 0; t < T_STEPS; t += 2) {
        STEP(0, e0);
        STEP(1, e1);
    }

    // h_last (i8) in buffer 0, rows 0-3
    if (tid < ROWS) {
        float s2 = 0.0f;
#pragma unroll
        for (int k = 0; k < NUNITS; k++)
            s2 += (float)zq[0][k >> 6][(k >> 4) & 3][tid][k & 15] * Wout[k];
        float s = s2 * (1.0f / 127.0f) + bout[0];
        out[r0 + tid] = __builtin_amdgcn_rcpf(1.0f + __builtin_amdgcn_exp2f(-LOG2E * s));
    }
}

extern "C" void kernel_launch(void* const* d_in, const int* in_sizes, int n_in,
                              void* d_out, int out_size, void* d_ws, size_t ws_size,
                              hipStream_t stream) {
    const float* x     = (const float*)d_in[0];
    const float* Wemb  = (const float*)d_in[1];
    const float* bemb  = (const float*)d_in[2];
    const float* Wf    = (const float*)d_in[3];
    const float* bf_   = (const float*)d_in[4];
    const float* Wi    = (const float*)d_in[5];
    const float* bi_   = (const float*)d_in[6];
    const float* Wg    = (const float*)d_in[7];
    const float* bg_   = (const float*)d_in[8];
    const float* Wo    = (const float*)d_in[9];
    const float* bo_   = (const float*)d_in[10];
    const float* Wout  = (const float*)d_in[11];
    const float* bout  = (const float*)d_in[12];
    float* out = (float*)d_out;
    uchar* e_ws = (uchar*)d_ws;   // [T][B][32] i8, 64 MB (+<=64KB overrun reads)

    int nrows = BATCH * T_STEPS;
    emb_kernel<<<nrows / 256, 256, 0, stream>>>(x, Wemb, bemb, e_ws);
    lstm_kernel<<<BATCH / ROWS, 512, 0, stream>>>(e_ws, Wf, bf_, Wi, bi_, Wg, bg_,
                                                  Wo, bo_, Wout, bout, out);
}